// Round 8
// baseline (96.906 us; speedup 1.0000x reference)
//
#include <hip/hip_runtime.h>

#define NUM_FEATURES 256
#define NUM_SAMPLES  262144
#define BATCH        1024

typedef float f4 __attribute__((ext_vector_type(4)));

#define COPY_BLOCKS 2048
#define COPY_THREADS 256

// ws layout: float rows[BATCH][NUM_FEATURES] (1 MiB) then int flags[BATCH] (4 KiB)
#define WS_ROWS_BYTES ((size_t)BATCH * NUM_FEATURES * sizeof(float))
#define WS_NEEDED     (WS_ROWS_BYTES + (size_t)BATCH * sizeof(int))

// Fused: BW-bound table copy (all 2048x256 threads) + latency-bound chain
// compute (wave 0 of blocks 0..1023) hidden under it. Chain results go to
// ws; a tiny scatter kernel applies them after the copy completes.
__global__ __launch_bounds__(COPY_THREADS) void fused_copy_chain(
    const float* __restrict__ inputs,
    const int*   __restrict__ targets,
    const float* __restrict__ features,
    float*       __restrict__ out,
    float*       __restrict__ ws_rows,
    int*         __restrict__ ws_flags)
{
    const int b    = blockIdx.x;
    const int wave = threadIdx.x >> 6;
    const int lane = threadIdx.x & 63;

    __shared__ int t[BATCH];  // touched only by wave 0 of blocks < BATCH

    if (b < BATCH && wave == 0) {
        // Stage all 1024 targets (wave-private LDS, no block barrier needed).
        const int4* tg4 = reinterpret_cast<const int4*>(targets);
        int4* t4 = reinterpret_cast<int4*>(t);
        #pragma unroll
        for (int k = 0; k < BATCH / 4 / 64; ++k)
            t4[k * 64 + lane] = tg4[k * 64 + lane];
        const int y = t[b];

        // Ownership: b is the first occurrence of y?
        bool owner = true;
        for (int base = 0; base < b; base += 64) {
            const int j = base + lane;
            if (__any(j < b && t[j] == y)) { owner = false; break; }
        }

        if (owner) {
            f4 v = reinterpret_cast<const f4*>(
                       features + (size_t)y * NUM_FEATURES)[lane];
            const float m  = 0.1f;
            const float om = 1.0f - m;
            for (int base = b & ~63; base < BATCH; base += 64) {
                const int i = base + lane;
                unsigned long long mask = __ballot(i >= b && t[i] == y);
                while (mask) {
                    const int i0 = base + (__ffsll((long long)mask) - 1);
                    mask &= mask - 1;
                    f4 x = reinterpret_cast<const f4*>(
                               inputs + (size_t)i0 * NUM_FEATURES)[lane];
                    v.x = m * v.x + om * x.x;
                    v.y = m * v.y + om * x.y;
                    v.z = m * v.z + om * x.z;
                    v.w = m * v.w + om * x.w;
                    float s = v.x * v.x + v.y * v.y + v.z * v.z + v.w * v.w;
                    #pragma unroll
                    for (int off = 32; off > 0; off >>= 1)
                        s += __shfl_xor(s, off);
                    const float inv = 1.0f / fmaxf(sqrtf(s), 1e-12f);
                    v.x *= inv; v.y *= inv; v.z *= inv; v.w *= inv;
                }
            }
            reinterpret_cast<f4*>(ws_rows + (size_t)b * NUM_FEATURES)[lane] = v;
        }
        if (lane == 0) ws_flags[b] = owner ? 1 : 0;
    }

    // Copy share: 2-deep pipelined grid-stride (R7 structure, 6.1 TB/s).
    const long gtid = (long)b * COPY_THREADS + threadIdx.x;
    const long T  = (long)COPY_BLOCKS * COPY_THREADS;      // 524288
    const long n4 = (long)NUM_SAMPLES * NUM_FEATURES / 4;  // 16777216 = 32*T
    const f4* src = reinterpret_cast<const f4*>(features);
    f4* dst = reinterpret_cast<f4*>(out);
    for (long i = gtid; i < n4; i += 2 * T) {
        f4 v0 = __builtin_nontemporal_load(&src[i]);
        f4 v1 = __builtin_nontemporal_load(&src[i + T]);
        dst[i] = v0;
        dst[i + T] = v1;
    }
}

// Pure scatter: overwrite the ~1022 owned rows with their final values.
__global__ __launch_bounds__(64) void scatter_rows(
    const int*   __restrict__ targets,
    const float* __restrict__ ws_rows,
    const int*   __restrict__ ws_flags,
    float*       __restrict__ out)
{
    const int b = blockIdx.x;
    if (!ws_flags[b]) return;
    const int lane = threadIdx.x;
    const int y = targets[b];
    f4 v = reinterpret_cast<const f4*>(ws_rows + (size_t)b * NUM_FEATURES)[lane];
    reinterpret_cast<f4*>(out + (size_t)y * NUM_FEATURES)[lane] = v;
}

// ---- R7 fallback path (used only if ws_size is too small) ----
__global__ __launch_bounds__(COPY_THREADS) void table_copy(
    const f4* __restrict__ src, f4* __restrict__ dst, long n4)
{
    const long tid = (long)blockIdx.x * COPY_THREADS + threadIdx.x;
    const long T = (long)COPY_BLOCKS * COPY_THREADS;
    for (long i = tid; i < n4; i += 2 * T) {
        f4 v0 = __builtin_nontemporal_load(&src[i]);
        f4 v1 = __builtin_nontemporal_load(&src[i + T]);
        dst[i] = v0;
        dst[i + T] = v1;
    }
}

__global__ __launch_bounds__(64) void memory_bank_update(
    const float* __restrict__ inputs,
    const int*   __restrict__ targets,
    const float* __restrict__ features,
    float*       __restrict__ out)
{
    __shared__ int t[BATCH];
    const int lane = threadIdx.x;
    const int b = blockIdx.x;

    const int4* tg4 = reinterpret_cast<const int4*>(targets);
    int4* t4 = reinterpret_cast<int4*>(t);
    #pragma unroll
    for (int k = 0; k < BATCH / 4 / 64; ++k)
        t4[k * 64 + lane] = tg4[k * 64 + lane];
    __syncthreads();

    const int y = t[b];
    for (int base = 0; base < b; base += 64) {
        const int j = base + lane;
        if (__any(j < b && t[j] == y)) return;
    }

    f4 v = reinterpret_cast<const f4*>(features + (size_t)y * NUM_FEATURES)[lane];
    const float m  = 0.1f;
    const float om = 1.0f - m;

    for (int base = b & ~63; base < BATCH; base += 64) {
        const int i = base + lane;
        unsigned long long mask = __ballot(i >= b && t[i] == y);
        while (mask) {
            const int i0 = base + (__ffsll((long long)mask) - 1);
            mask &= mask - 1;
            f4 x = reinterpret_cast<const f4*>(
                       inputs + (size_t)i0 * NUM_FEATURES)[lane];
            v.x = m * v.x + om * x.x;
            v.y = m * v.y + om * x.y;
            v.z = m * v.z + om * x.z;
            v.w = m * v.w + om * x.w;
            float s = v.x * v.x + v.y * v.y + v.z * v.z + v.w * v.w;
            #pragma unroll
            for (int off = 32; off > 0; off >>= 1)
                s += __shfl_xor(s, off);
            const float inv = 1.0f / fmaxf(sqrtf(s), 1e-12f);
            v.x *= inv; v.y *= inv; v.z *= inv; v.w *= inv;
        }
    }
    reinterpret_cast<f4*>(out + (size_t)y * NUM_FEATURES)[lane] = v;
}

extern "C" void kernel_launch(void* const* d_in, const int* in_sizes, int n_in,
                              void* d_out, int out_size, void* d_ws, size_t ws_size,
                              hipStream_t stream) {
    const float* inputs   = (const float*)d_in[0];
    const int*   targets  = (const int*)d_in[1];
    const float* features = (const float*)d_in[2];
    float*       out      = (float*)d_out;
    const long n4 = (long)NUM_SAMPLES * NUM_FEATURES / 4;

    if (ws_size >= WS_NEEDED) {
        float* ws_rows  = (float*)d_ws;
        int*   ws_flags = (int*)((char*)d_ws + WS_ROWS_BYTES);
        fused_copy_chain<<<COPY_BLOCKS, COPY_THREADS, 0, stream>>>(
            inputs, targets, features, out, ws_rows, ws_flags);
        scatter_rows<<<BATCH, 64, 0, stream>>>(targets, ws_rows, ws_flags, out);
    } else {
        table_copy<<<COPY_BLOCKS, COPY_THREADS, 0, stream>>>(
            reinterpret_cast<const f4*>(features),
            reinterpret_cast<f4*>(out), n4);
        memory_bank_update<<<BATCH, 64, 0, stream>>>(inputs, targets, features, out);
    }
}

// Round 9
// 89.273 us; speedup vs baseline: 1.0855x; 1.0855x over previous
//
#include <hip/hip_runtime.h>

#define NUM_FEATURES 256
#define NUM_SAMPLES  262144
#define BATCH        1024

typedef float f4 __attribute__((ext_vector_type(4)));

#define COPY_BLOCKS 2048
#define COPY_THREADS 256
// 16777216 f4 total / 2048 blocks = 8192 f4 (128 KiB) contiguous per block.

// Block-contiguous streaming copy: block b owns f4[b*8192 .. b*8192+8192).
// Per iteration each thread issues 4 independent loads 4 KiB apart (batched
// before the stores drain them) -> 4-deep ILP with a 64 KiB per-block
// sliding window: max DRAM page locality, unlike R5's 64 MiB-wide streams.
__global__ __launch_bounds__(COPY_THREADS) void table_copy(
    const f4* __restrict__ src, f4* __restrict__ dst)
{
    const long base = (long)blockIdx.x * 8192 + threadIdx.x;
    #pragma unroll 1
    for (int k = 0; k < 8; ++k) {
        const long i = base + (long)k * 1024;
        f4 v0 = __builtin_nontemporal_load(&src[i]);
        f4 v1 = __builtin_nontemporal_load(&src[i + 256]);
        f4 v2 = __builtin_nontemporal_load(&src[i + 512]);
        f4 v3 = __builtin_nontemporal_load(&src[i + 768]);
        dst[i]       = v0;
        dst[i + 256] = v1;
        dst[i + 512] = v2;
        dst[i + 768] = v3;
    }
}

// One wave per batch entry. Block b owns target y = targets[b] iff b is the
// FIRST occurrence of y. Targets staged in LDS; ownership check and chain
// scan are ballot-based (<=16 iterations), not serial global loads.
__global__ __launch_bounds__(64) void memory_bank_update(
    const float* __restrict__ inputs,    // [BATCH, F]
    const int*   __restrict__ targets,   // [BATCH]
    const float* __restrict__ features,  // [NUM_SAMPLES, F] (original table)
    float*       __restrict__ out)       // [NUM_SAMPLES, F] (already copied)
{
    __shared__ int t[BATCH];
    const int lane = threadIdx.x;  // 0..63
    const int b = blockIdx.x;

    // Stage all 1024 targets: 4 rounds of coalesced int4 loads.
    const int4* tg4 = reinterpret_cast<const int4*>(targets);
    int4* t4 = reinterpret_cast<int4*>(t);
    #pragma unroll
    for (int k = 0; k < BATCH / 4 / 64; ++k)
        t4[k * 64 + lane] = tg4[k * 64 + lane];
    __syncthreads();

    const int y = t[b];

    // Ownership: does y appear in t[0..b-1]?  Ballot over 64-wide chunks.
    for (int base = 0; base < b; base += 64) {
        const int j = base + lane;
        if (__any(j < b && t[j] == y)) return;  // earlier occurrence owns it
    }

    f4 v = reinterpret_cast<const f4*>(features + (size_t)y * NUM_FEATURES)[lane];

    const float m  = 0.1f;
    const float om = 1.0f - m;

    // Chain scan: all i in [b, BATCH) with t[i]==y, in order, via ballot+ffs.
    for (int base = b & ~63; base < BATCH; base += 64) {
        const int i = base + lane;
        unsigned long long mask = __ballot(i >= b && t[i] == y);
        while (mask) {
            const int i0 = base + (__ffsll((long long)mask) - 1);
            mask &= mask - 1;

            f4 x = reinterpret_cast<const f4*>(
                       inputs + (size_t)i0 * NUM_FEATURES)[lane];
            v.x = m * v.x + om * x.x;
            v.y = m * v.y + om * x.y;
            v.z = m * v.z + om * x.z;
            v.w = m * v.w + om * x.w;

            float s = v.x * v.x + v.y * v.y + v.z * v.z + v.w * v.w;
            #pragma unroll
            for (int off = 32; off > 0; off >>= 1)
                s += __shfl_xor(s, off);

            const float inv = 1.0f / fmaxf(sqrtf(s), 1e-12f);
            v.x *= inv; v.y *= inv; v.z *= inv; v.w *= inv;
        }
    }

    reinterpret_cast<f4*>(out + (size_t)y * NUM_FEATURES)[lane] = v;
}

extern "C" void kernel_launch(void* const* d_in, const int* in_sizes, int n_in,
                              void* d_out, int out_size, void* d_ws, size_t ws_size,
                              hipStream_t stream) {
    const float* inputs   = (const float*)d_in[0];
    const int*   targets  = (const int*)d_in[1];
    const float* features = (const float*)d_in[2];
    float*       out      = (float*)d_out;

    table_copy<<<COPY_BLOCKS, COPY_THREADS, 0, stream>>>(
        reinterpret_cast<const f4*>(features),
        reinterpret_cast<f4*>(out));

    // Then overwrite the 1024 touched rows with the chained updates.
    memory_bank_update<<<BATCH, 64, 0, stream>>>(inputs, targets, features, out);
}